// Round 3
// baseline (317.222 us; speedup 1.0000x reference)
//
#include <hip/hip_runtime.h>
#include <hip/hip_cooperative_groups.h>
#include <math.h>

namespace cg = cooperative_groups;

#define BLK 256
#define IT 2
#define JSPLIT 64          // fused path: 16 i-tiles x 64 j-splits = 1024 blocks = 4/CU
#define NBLOCKS 1024
#define LAM 0.1f

// ws layout (floats): probs[4N] | rows[5N] | scal[16] | kpart[32*12]
// scal[0..3] = T_ce raw. kpart[b][0..11] = focal,W,M1[5],M2[5]

__device__ __forceinline__ float wave_reduce(float v) {
    v += __shfl_down(v, 32, 64);
    v += __shfl_down(v, 16, 64);
    v += __shfl_down(v, 8, 64);
    v += __shfl_down(v, 4, 64);
    v += __shfl_down(v, 2, 64);
    v += __shfl_down(v, 1, 64);
    return v;
}

// ================= fused cooperative kernel =================
__global__ __launch_bounds__(BLK, 4) void fused_all(
        const float* __restrict__ outs, const int* __restrict__ labels,
        const float* __restrict__ event, const float* __restrict__ wts,
        float* __restrict__ probs, float* __restrict__ rows,
        float* __restrict__ scal, float* __restrict__ kpart,
        float* __restrict__ out, int N) {
    cg::grid_group grid = cg::this_grid();

    __shared__ float4 jp[128];
    __shared__ float2 jew[128];
    __shared__ float red[16][14];
    __shared__ float fin[12];

    int tid = threadIdx.x;
    int b = blockIdx.x;
    int lane = tid & 63, wave = tid >> 6;

    // ---------- phase A: zero accumulators + row prep ----------
    {
        int gid = b * BLK + tid;
        if (gid < 5 * N + 16) rows[gid] = 0.f;  // rows + scal (contiguous)

        if (b < N / BLK) {  // first 32 blocks do the per-row prep
            int i = b * BLK + tid;
            float4 o = ((const float4*)outs)[i];
            float m = fmaxf(fmaxf(o.x, o.y), fmaxf(o.z, o.w));
            float e0 = expf(o.x - m), e1 = expf(o.y - m),
                  e2 = expf(o.z - m), e3 = expf(o.w - m);
            float s = e0 + e1 + e2 + e3;
            float inv = 1.0f / s;
            float4 p = make_float4(e0 * inv, e1 * inv, e2 * inv, e3 * inv);
            ((float4*)probs)[i] = p;

            int l = labels[i];
            float ol = (l == 0) ? o.x : (l == 1) ? o.y : (l == 2) ? o.z : o.w;
            float logpt = ol - m - logf(s);
            float pt = expf(logpt);
            float w = wts[i];
            float ev = event[i];
            float om = 1.0f - pt;
            float focal = -om * om * logpt * w;

            float vals[12] = {focal, w,
                              w * p.x, w * p.y, w * p.z, w * p.w, w * ev,
                              w * p.x * p.x, w * p.y * p.y, w * p.z * p.z,
                              w * p.w * p.w, w * ev * ev};
#pragma unroll
            for (int k = 0; k < 12; ++k) {
                float r = wave_reduce(vals[k]);
                if (lane == 0) red[wave][k] = r;
            }
            __syncthreads();
            if (tid < 12)
                kpart[b * 12 + tid] =
                    red[0][tid] + red[1][tid] + red[2][tid] + red[3][tid];
        }
    }

    grid.sync();

    // ---------- phase B: O(N^2) pair pass ----------
    {
        int itile = b & 15;          // 16 i-tiles
        int jsp = b >> 4;            // 64 j-splits
        int jcount = N / JSPLIT;     // 128
        int jbase = jsp * jcount;

        int i0 = itile * (BLK * IT) + tid;
        int i1 = i0 + BLK;
        float4 pA = ((const float4*)probs)[i0];
        float4 pB = ((const float4*)probs)[i1];
        float eA = event[i0], eB = event[i1];
        float wA = wts[i0], wB = wts[i1];

        if (tid < 128) {
            int j = jbase + tid;
            jp[tid] = ((const float4*)probs)[j];
            jew[tid] = make_float2(event[j], wts[j]);
        }
        __syncthreads();

        float sA0 = 0.f, sA1 = 0.f, sA2 = 0.f, sA3 = 0.f, sAe = 0.f;
        float sB0 = 0.f, sB1 = 0.f, sB2 = 0.f, sB3 = 0.f, sBe = 0.f;
        float tA0 = 0.f, tA1 = 0.f, tA2 = 0.f, tA3 = 0.f;
        float tB0 = 0.f, tB1 = 0.f, tB2 = 0.f, tB3 = 0.f;

#pragma unroll 4
        for (int jj = 0; jj < 128; ++jj) {
            float4 p = jp[jj];
            float2 ew = jew[jj];
            float wj = ew.y;
            {
                float d0 = fabsf(pA.x - p.x);
                float d1 = fabsf(pA.y - p.y);
                float d2 = fabsf(pA.z - p.z);
                float d3 = fabsf(pA.w - p.w);
                float de = fabsf(eA - ew.x);
                sA0 = fmaf(wj, d0, sA0);
                sA1 = fmaf(wj, d1, sA1);
                sA2 = fmaf(wj, d2, sA2);
                sA3 = fmaf(wj, d3, sA3);
                sAe = fmaf(wj, de, sAe);
                float wde = wj * de;
                tA0 = fmaf(wde, d0, tA0);
                tA1 = fmaf(wde, d1, tA1);
                tA2 = fmaf(wde, d2, tA2);
                tA3 = fmaf(wde, d3, tA3);
            }
            {
                float d0 = fabsf(pB.x - p.x);
                float d1 = fabsf(pB.y - p.y);
                float d2 = fabsf(pB.z - p.z);
                float d3 = fabsf(pB.w - p.w);
                float de = fabsf(eB - ew.x);
                sB0 = fmaf(wj, d0, sB0);
                sB1 = fmaf(wj, d1, sB1);
                sB2 = fmaf(wj, d2, sB2);
                sB3 = fmaf(wj, d3, sB3);
                sBe = fmaf(wj, de, sBe);
                float wde = wj * de;
                tB0 = fmaf(wde, d0, tB0);
                tB1 = fmaf(wde, d1, tB1);
                tB2 = fmaf(wde, d2, tB2);
                tB3 = fmaf(wde, d3, tB3);
            }
        }

        atomicAdd(&rows[0 * N + i0], sA0);
        atomicAdd(&rows[1 * N + i0], sA1);
        atomicAdd(&rows[2 * N + i0], sA2);
        atomicAdd(&rows[3 * N + i0], sA3);
        atomicAdd(&rows[4 * N + i0], sAe);
        atomicAdd(&rows[0 * N + i1], sB0);
        atomicAdd(&rows[1 * N + i1], sB1);
        atomicAdd(&rows[2 * N + i1], sB2);
        atomicAdd(&rows[3 * N + i1], sB3);
        atomicAdd(&rows[4 * N + i1], sBe);

        float t0 = tA0 * wA + tB0 * wB;
        float t1 = tA1 * wA + tB1 * wB;
        float t2 = tA2 * wA + tB2 * wB;
        float t3 = tA3 * wA + tB3 * wB;
        t0 = wave_reduce(t0); t1 = wave_reduce(t1);
        t2 = wave_reduce(t2); t3 = wave_reduce(t3);
        __syncthreads();  // jp/jew reads done before red reuse
        if (lane == 0) {
            red[wave][0] = t0; red[wave][1] = t1;
            red[wave][2] = t2; red[wave][3] = t3;
        }
        __syncthreads();
        if (tid < 4)
            atomicAdd(&scal[tid],
                      red[0][tid] + red[1][tid] + red[2][tid] + red[3][tid]);
    }

    grid.sync();

    // ---------- phase C: final reduction + scalar math (block 0) ----------
    if (b == 0) {
        if (wave == 0) {
#pragma unroll
            for (int k = 0; k < 12; ++k) {
                float v = (lane < 32) ? kpart[lane * 12 + k] : 0.f;
                v = wave_reduce(v);
                if (lane == 0) fin[k] = v;
            }
        }

        float acc[14];
#pragma unroll
        for (int k = 0; k < 14; ++k) acc[k] = 0.f;

        for (int i = tid; i < N; i += BLK) {
            float w = wts[i];
            float s0 = rows[0 * N + i], s1 = rows[1 * N + i],
                  s2 = rows[2 * N + i], s3 = rows[3 * N + i],
                  sE = rows[4 * N + i];
            acc[0] += w * s0; acc[1] += w * s1; acc[2] += w * s2;
            acc[3] += w * s3; acc[4] += w * sE;
            float wE = w * sE;
            acc[5] += wE * s0; acc[6] += wE * s1;
            acc[7] += wE * s2; acc[8] += wE * s3;
            acc[9] += wE * sE;
            acc[10] += w * s0 * s0; acc[11] += w * s1 * s1;
            acc[12] += w * s2 * s2; acc[13] += w * s3 * s3;
        }

#pragma unroll
        for (int k = 0; k < 14; ++k) acc[k] = wave_reduce(acc[k]);
        __syncthreads();
        if (lane == 0) {
#pragma unroll
            for (int k = 0; k < 14; ++k) red[wave][k] = acc[k];
        }
        __syncthreads();

        if (tid == 0) {
            float SW[5], SWW_ce[4], SWW_ee, SWW_cc[4];
#pragma unroll
            for (int k = 0; k < 5; ++k)
                SW[k] = red[0][k] + red[1][k] + red[2][k] + red[3][k];
#pragma unroll
            for (int k = 0; k < 4; ++k)
                SWW_ce[k] = red[0][5 + k] + red[1][5 + k] + red[2][5 + k] + red[3][5 + k];
            SWW_ee = red[0][9] + red[1][9] + red[2][9] + red[3][9];
#pragma unroll
            for (int k = 0; k < 4; ++k)
                SWW_cc[k] = red[0][10 + k] + red[1][10 + k] + red[2][10 + k] + red[3][10 + k];

            float focal_sum = fin[0];
            float W = fin[1];
            float M1[5] = {fin[2], fin[3], fin[4], fin[5], fin[6]};
            float M2[5] = {fin[7], fin[8], fin[9], fin[10], fin[11]};

            float invW2 = 1.0f / (W * W);
            float invW3 = invW2 / W;

            float g[5];
#pragma unroll
            for (int v = 0; v < 5; ++v) g[v] = SW[v] * invW2;
            float gE = g[4];

            float Tee = 2.0f * (W * M2[4] - M1[4] * M1[4]);
            float num_ee = Tee * invW2 - 2.0f * SWW_ee * invW3 + gE * gE;

            float disco = 0.f;
#pragma unroll
            for (int c = 0; c < 4; ++c) {
                float Tcc = 2.0f * (W * M2[c] - M1[c] * M1[c]);
                float num_cc = Tcc * invW2 - 2.0f * SWW_cc[c] * invW3 + g[c] * g[c];
                float num_ce = scal[c] * invW2 - 2.0f * SWW_ce[c] * invW3 + g[c] * gE;
                disco += num_ce * rsqrtf(num_cc * num_ee);
            }
            disco *= 0.25f;

            float f = focal_sum / (float)N;
            out[0] = f;
            out[1] = disco;
            out[2] = f + LAM * disco;
        }
    }
}

// ================= fallback path (3 discrete kernels) =================
__global__ __launch_bounds__(BLK) void k1_rowprep(
        const float* __restrict__ outs, const int* __restrict__ labels,
        const float* __restrict__ event, const float* __restrict__ wts,
        float* __restrict__ probs, float* __restrict__ rows,
        float* __restrict__ scal, float* __restrict__ kpart, int N) {
    __shared__ float red[4][12];
    int i = blockIdx.x * BLK + threadIdx.x;
    float4 o = ((const float4*)outs)[i];
    float m = fmaxf(fmaxf(o.x, o.y), fmaxf(o.z, o.w));
    float e0 = expf(o.x - m), e1 = expf(o.y - m), e2 = expf(o.z - m), e3 = expf(o.w - m);
    float s = e0 + e1 + e2 + e3;
    float inv = 1.0f / s;
    float4 p = make_float4(e0 * inv, e1 * inv, e2 * inv, e3 * inv);
    ((float4*)probs)[i] = p;
    int l = labels[i];
    float ol = (l == 0) ? o.x : (l == 1) ? o.y : (l == 2) ? o.z : o.w;
    float logpt = ol - m - logf(s);
    float pt = expf(logpt);
    float w = wts[i];
    float ev = event[i];
    float om = 1.0f - pt;
    float focal = -om * om * logpt * w;
#pragma unroll
    for (int v = 0; v < 5; ++v) rows[v * N + i] = 0.f;
    if (blockIdx.x == 0 && threadIdx.x < 16) scal[threadIdx.x] = 0.f;
    float vals[12] = {focal, w, w * p.x, w * p.y, w * p.z, w * p.w, w * ev,
                      w * p.x * p.x, w * p.y * p.y, w * p.z * p.z,
                      w * p.w * p.w, w * ev * ev};
    int lane = threadIdx.x & 63, wave = threadIdx.x >> 6;
#pragma unroll
    for (int k = 0; k < 12; ++k) {
        float r = wave_reduce(vals[k]);
        if (lane == 0) red[wave][k] = r;
    }
    __syncthreads();
    if (threadIdx.x < 12)
        kpart[blockIdx.x * 12 + threadIdx.x] =
            red[0][threadIdx.x] + red[1][threadIdx.x] + red[2][threadIdx.x] + red[3][threadIdx.x];
}

__global__ __launch_bounds__(BLK) void k2_pairs(
        const float* __restrict__ probs, const float* __restrict__ event,
        const float* __restrict__ wts, float* __restrict__ rows,
        float* __restrict__ scal, int N) {
    __shared__ float4 jp[128];
    __shared__ float2 jew[128];
    __shared__ float red[4][4];
    int tid = threadIdx.x;
    int itile = blockIdx.x, jsp = blockIdx.y;
    int jcount = N / JSPLIT, jbase = jsp * jcount;
    int i0 = itile * (BLK * IT) + tid, i1 = i0 + BLK;
    float4 pA = ((const float4*)probs)[i0];
    float4 pB = ((const float4*)probs)[i1];
    float eA = event[i0], eB = event[i1];
    float wA = wts[i0], wB = wts[i1];
    if (tid < 128) {
        int j = jbase + tid;
        jp[tid] = ((const float4*)probs)[j];
        jew[tid] = make_float2(event[j], wts[j]);
    }
    __syncthreads();
    float sA0 = 0.f, sA1 = 0.f, sA2 = 0.f, sA3 = 0.f, sAe = 0.f;
    float sB0 = 0.f, sB1 = 0.f, sB2 = 0.f, sB3 = 0.f, sBe = 0.f;
    float tA0 = 0.f, tA1 = 0.f, tA2 = 0.f, tA3 = 0.f;
    float tB0 = 0.f, tB1 = 0.f, tB2 = 0.f, tB3 = 0.f;
#pragma unroll 4
    for (int jj = 0; jj < 128; ++jj) {
        float4 p = jp[jj];
        float2 ew = jew[jj];
        float wj = ew.y;
        {
            float d0 = fabsf(pA.x - p.x), d1 = fabsf(pA.y - p.y);
            float d2 = fabsf(pA.z - p.z), d3 = fabsf(pA.w - p.w);
            float de = fabsf(eA - ew.x);
            sA0 = fmaf(wj, d0, sA0); sA1 = fmaf(wj, d1, sA1);
            sA2 = fmaf(wj, d2, sA2); sA3 = fmaf(wj, d3, sA3);
            sAe = fmaf(wj, de, sAe);
            float wde = wj * de;
            tA0 = fmaf(wde, d0, tA0); tA1 = fmaf(wde, d1, tA1);
            tA2 = fmaf(wde, d2, tA2); tA3 = fmaf(wde, d3, tA3);
        }
        {
            float d0 = fabsf(pB.x - p.x), d1 = fabsf(pB.y - p.y);
            float d2 = fabsf(pB.z - p.z), d3 = fabsf(pB.w - p.w);
            float de = fabsf(eB - ew.x);
            sB0 = fmaf(wj, d0, sB0); sB1 = fmaf(wj, d1, sB1);
            sB2 = fmaf(wj, d2, sB2); sB3 = fmaf(wj, d3, sB3);
            sBe = fmaf(wj, de, sBe);
            float wde = wj * de;
            tB0 = fmaf(wde, d0, tB0); tB1 = fmaf(wde, d1, tB1);
            tB2 = fmaf(wde, d2, tB2); tB3 = fmaf(wde, d3, tB3);
        }
    }
    atomicAdd(&rows[0 * N + i0], sA0); atomicAdd(&rows[1 * N + i0], sA1);
    atomicAdd(&rows[2 * N + i0], sA2); atomicAdd(&rows[3 * N + i0], sA3);
    atomicAdd(&rows[4 * N + i0], sAe);
    atomicAdd(&rows[0 * N + i1], sB0); atomicAdd(&rows[1 * N + i1], sB1);
    atomicAdd(&rows[2 * N + i1], sB2); atomicAdd(&rows[3 * N + i1], sB3);
    atomicAdd(&rows[4 * N + i1], sBe);
    float t0 = tA0 * wA + tB0 * wB, t1 = tA1 * wA + tB1 * wB;
    float t2 = tA2 * wA + tB2 * wB, t3 = tA3 * wA + tB3 * wB;
    int lane = tid & 63, wave = tid >> 6;
    t0 = wave_reduce(t0); t1 = wave_reduce(t1);
    t2 = wave_reduce(t2); t3 = wave_reduce(t3);
    if (lane == 0) {
        red[wave][0] = t0; red[wave][1] = t1;
        red[wave][2] = t2; red[wave][3] = t3;
    }
    __syncthreads();
    if (tid < 4)
        atomicAdd(&scal[tid], red[0][tid] + red[1][tid] + red[2][tid] + red[3][tid]);
}

__global__ __launch_bounds__(1024) void k3_final(
        const float* __restrict__ rows, const float* __restrict__ scal,
        const float* __restrict__ wts, const float* __restrict__ kpart,
        float* __restrict__ out, int N) {
    __shared__ float red[16][14];
    __shared__ float fin[12];
    int tid = threadIdx.x, lane = tid & 63, wave = tid >> 6;
    if (wave == 0) {
#pragma unroll
        for (int k = 0; k < 12; ++k) {
            float v = (lane < 32) ? kpart[lane * 12 + k] : 0.f;
            v = wave_reduce(v);
            if (lane == 0) fin[k] = v;
        }
    }
    float acc[14];
#pragma unroll
    for (int k = 0; k < 14; ++k) acc[k] = 0.f;
    for (int i = tid; i < N; i += 1024) {
        float w = wts[i];
        float s0 = rows[0 * N + i], s1 = rows[1 * N + i], s2 = rows[2 * N + i],
              s3 = rows[3 * N + i], sE = rows[4 * N + i];
        acc[0] += w * s0; acc[1] += w * s1; acc[2] += w * s2;
        acc[3] += w * s3; acc[4] += w * sE;
        float wE = w * sE;
        acc[5] += wE * s0; acc[6] += wE * s1; acc[7] += wE * s2; acc[8] += wE * s3;
        acc[9] += wE * sE;
        acc[10] += w * s0 * s0; acc[11] += w * s1 * s1;
        acc[12] += w * s2 * s2; acc[13] += w * s3 * s3;
    }
#pragma unroll
    for (int k = 0; k < 14; ++k) acc[k] = wave_reduce(acc[k]);
    if (lane == 0) {
#pragma unroll
        for (int k = 0; k < 14; ++k) red[wave][k] = acc[k];
    }
    __syncthreads();
    if (tid == 0) {
        float SW[5], SWW_ce[4], SWW_ee, SWW_cc[4];
#pragma unroll
        for (int k = 0; k < 5; ++k) {
            float a = 0.f;
            for (int wv = 0; wv < 16; ++wv) a += red[wv][k];
            SW[k] = a;
        }
#pragma unroll
        for (int k = 0; k < 4; ++k) {
            float a = 0.f;
            for (int wv = 0; wv < 16; ++wv) a += red[wv][5 + k];
            SWW_ce[k] = a;
        }
        {
            float a = 0.f;
            for (int wv = 0; wv < 16; ++wv) a += red[wv][9];
            SWW_ee = a;
        }
#pragma unroll
        for (int k = 0; k < 4; ++k) {
            float a = 0.f;
            for (int wv = 0; wv < 16; ++wv) a += red[wv][10 + k];
            SWW_cc[k] = a;
        }
        float focal_sum = fin[0];
        float W = fin[1];
        float M1[5] = {fin[2], fin[3], fin[4], fin[5], fin[6]};
        float M2[5] = {fin[7], fin[8], fin[9], fin[10], fin[11]};
        float invW2 = 1.0f / (W * W);
        float invW3 = invW2 / W;
        float g[5];
#pragma unroll
        for (int v = 0; v < 5; ++v) g[v] = SW[v] * invW2;
        float gE = g[4];
        float Tee = 2.0f * (W * M2[4] - M1[4] * M1[4]);
        float num_ee = Tee * invW2 - 2.0f * SWW_ee * invW3 + gE * gE;
        float disco = 0.f;
#pragma unroll
        for (int c = 0; c < 4; ++c) {
            float Tcc = 2.0f * (W * M2[c] - M1[c] * M1[c]);
            float num_cc = Tcc * invW2 - 2.0f * SWW_cc[c] * invW3 + g[c] * g[c];
            float num_ce = scal[c] * invW2 - 2.0f * SWW_ce[c] * invW3 + g[c] * gE;
            disco += num_ce * rsqrtf(num_cc * num_ee);
        }
        disco *= 0.25f;
        float f = focal_sum / (float)N;
        out[0] = f;
        out[1] = disco;
        out[2] = f + LAM * disco;
    }
}

extern "C" void kernel_launch(void* const* d_in, const int* in_sizes, int n_in,
                              void* d_out, int out_size, void* d_ws, size_t ws_size,
                              hipStream_t stream) {
    const float* outs = (const float*)d_in[0];
    const int* labels = (const int*)d_in[1];
    const float* event = (const float*)d_in[2];
    const float* wts = (const float*)d_in[3];
    float* out = (float*)d_out;
    int N = in_sizes[1];  // 8192

    float* ws = (float*)d_ws;
    float* probs = ws;                    // 4N
    float* rows = probs + (size_t)N * 4;  // 5N
    float* scal = rows + (size_t)N * 5;   // 16
    float* kpart = scal + 16;             // 32*12

    void* args[] = {(void*)&outs, (void*)&labels, (void*)&event, (void*)&wts,
                    (void*)&probs, (void*)&rows, (void*)&scal, (void*)&kpart,
                    (void*)&out, (void*)&N};
    hipError_t err = hipLaunchCooperativeKernel(
        (const void*)fused_all, dim3(NBLOCKS), dim3(BLK), args, 0, stream);

    if (err != hipSuccess) {
        // fallback: discrete kernels (same math)
        k1_rowprep<<<N / BLK, BLK, 0, stream>>>(outs, labels, event, wts, probs,
                                                rows, scal, kpart, N);
        dim3 g2(N / (BLK * IT), JSPLIT);
        k2_pairs<<<g2, BLK, 0, stream>>>(probs, event, wts, rows, scal, N);
        k3_final<<<1, 1024, 0, stream>>>(rows, scal, wts, kpart, out, N);
    }
}

// Round 4
// 107.192 us; speedup vs baseline: 2.9594x; 2.9594x over previous
//
#include <hip/hip_runtime.h>
#include <math.h>

#define BLK 256
#define IT 4
#define JSPLIT 128
#define LAM 0.1f

// ws layout (floats): probs[4N] | rows[5N] | scal[16] | kpart[32*12]
// scal[0..3] = T_ce raw. kpart[b][0..11] = focal,W,M1[5],M2[5]

__device__ __forceinline__ float wave_reduce(float v) {
    v += __shfl_down(v, 32, 64);
    v += __shfl_down(v, 16, 64);
    v += __shfl_down(v, 8, 64);
    v += __shfl_down(v, 4, 64);
    v += __shfl_down(v, 2, 64);
    v += __shfl_down(v, 1, 64);
    return v;
}

// ---------------- kernel 1: softmax + focal + moments + zero accumulators ----
__global__ __launch_bounds__(BLK) void k1_rowprep(
        const float* __restrict__ outs, const int* __restrict__ labels,
        const float* __restrict__ event, const float* __restrict__ wts,
        float* __restrict__ probs, float* __restrict__ rows,
        float* __restrict__ scal, float* __restrict__ kpart, int N) {
    __shared__ float red[4][12];
    int i = blockIdx.x * BLK + threadIdx.x;
    float4 o = ((const float4*)outs)[i];
    float m = fmaxf(fmaxf(o.x, o.y), fmaxf(o.z, o.w));
    float e0 = expf(o.x - m), e1 = expf(o.y - m), e2 = expf(o.z - m), e3 = expf(o.w - m);
    float s = e0 + e1 + e2 + e3;
    float inv = 1.0f / s;
    float4 p = make_float4(e0 * inv, e1 * inv, e2 * inv, e3 * inv);
    ((float4*)probs)[i] = p;

    int l = labels[i];
    float ol = (l == 0) ? o.x : (l == 1) ? o.y : (l == 2) ? o.z : o.w;
    float logpt = ol - m - logf(s);
    float pt = expf(logpt);
    float w = wts[i];
    float ev = event[i];
    float om = 1.0f - pt;
    float focal = -om * om * logpt * w;

    // zero row-sum accumulators + scal (k2 atomics land here; k1 completes first)
#pragma unroll
    for (int v = 0; v < 5; ++v) rows[v * N + i] = 0.f;
    if (blockIdx.x == 0 && threadIdx.x < 16) scal[threadIdx.x] = 0.f;

    float vals[12] = {focal, w,
                      w * p.x, w * p.y, w * p.z, w * p.w, w * ev,
                      w * p.x * p.x, w * p.y * p.y, w * p.z * p.z,
                      w * p.w * p.w, w * ev * ev};
    int lane = threadIdx.x & 63, wave = threadIdx.x >> 6;
#pragma unroll
    for (int k = 0; k < 12; ++k) {
        float r = wave_reduce(vals[k]);
        if (lane == 0) red[wave][k] = r;
    }
    __syncthreads();
    if (threadIdx.x < 12)
        kpart[blockIdx.x * 12 + threadIdx.x] =
            red[0][threadIdx.x] + red[1][threadIdx.x] + red[2][threadIdx.x] + red[3][threadIdx.x];
}

// ---------------- kernel 2: O(N^2) pair pass, IT=4 i-points/thread ----------
// grid (N/(BLK*IT), JSPLIT) = (8, 128) = 1024 blocks = 4 blocks/CU
__global__ __launch_bounds__(BLK) void k2_pairs(
        const float4* __restrict__ probs4, const float* __restrict__ event,
        const float* __restrict__ wts, float* __restrict__ rows,
        float* __restrict__ scal, int N) {
    __shared__ float4 jp[64];
    __shared__ float2 jew[64];
    __shared__ float red[4][4];

    int tid = threadIdx.x;
    int itile = blockIdx.x;        // 0..7
    int jsp = blockIdx.y;          // 0..127
    int jcount = N / JSPLIT;       // 64
    int jbase = jsp * jcount;
    int ibase = itile * (BLK * IT) + tid;

    float4 pi[IT];
    float ei[IT], wi[IT];
#pragma unroll
    for (int k = 0; k < IT; ++k) {
        int i = ibase + k * BLK;
        pi[k] = probs4[i];
        ei[k] = event[i];
        wi[k] = wts[i];
    }

    if (tid < 64) {
        int j = jbase + tid;
        jp[tid] = probs4[j];
        jew[tid] = make_float2(event[j], wts[j]);
    }
    __syncthreads();

    float s[IT][5], t[IT][4];
#pragma unroll
    for (int k = 0; k < IT; ++k) {
#pragma unroll
        for (int v = 0; v < 5; ++v) s[k][v] = 0.f;
#pragma unroll
        for (int v = 0; v < 4; ++v) t[k][v] = 0.f;
    }

#pragma unroll 8
    for (int jj = 0; jj < 64; ++jj) {
        float4 p = jp[jj];
        float2 ew = jew[jj];
        float wj = ew.y;
#pragma unroll
        for (int k = 0; k < IT; ++k) {
            float d0 = pi[k].x - p.x;
            float d1 = pi[k].y - p.y;
            float d2 = pi[k].z - p.z;
            float d3 = pi[k].w - p.w;
            float de = ei[k] - ew.x;
            // abs folds as VOP3 source modifier on the fma/mul
            s[k][0] = fmaf(wj, fabsf(d0), s[k][0]);
            s[k][1] = fmaf(wj, fabsf(d1), s[k][1]);
            s[k][2] = fmaf(wj, fabsf(d2), s[k][2]);
            s[k][3] = fmaf(wj, fabsf(d3), s[k][3]);
            float wde = wj * fabsf(de);
            s[k][4] += wde;
            t[k][0] = fmaf(wde, fabsf(d0), t[k][0]);
            t[k][1] = fmaf(wde, fabsf(d1), t[k][1]);
            t[k][2] = fmaf(wde, fabsf(d2), t[k][2]);
            t[k][3] = fmaf(wde, fabsf(d3), t[k][3]);
        }
    }

    // per-i raw row sums (accumulate across j-splits)
#pragma unroll
    for (int k = 0; k < IT; ++k) {
        int i = ibase + k * BLK;
        atomicAdd(&rows[0 * N + i], s[k][0]);
        atomicAdd(&rows[1 * N + i], s[k][1]);
        atomicAdd(&rows[2 * N + i], s[k][2]);
        atomicAdd(&rows[3 * N + i], s[k][3]);
        atomicAdd(&rows[4 * N + i], s[k][4]);
    }

    // T_ce partials: scale by w_i, block-reduce, 4 atomics per block
    float tc0 = t[0][0] * wi[0] + t[1][0] * wi[1] + t[2][0] * wi[2] + t[3][0] * wi[3];
    float tc1 = t[0][1] * wi[0] + t[1][1] * wi[1] + t[2][1] * wi[2] + t[3][1] * wi[3];
    float tc2 = t[0][2] * wi[0] + t[1][2] * wi[1] + t[2][2] * wi[2] + t[3][2] * wi[3];
    float tc3 = t[0][3] * wi[0] + t[1][3] * wi[1] + t[2][3] * wi[2] + t[3][3] * wi[3];
    int lane = tid & 63, wave = tid >> 6;
    tc0 = wave_reduce(tc0); tc1 = wave_reduce(tc1);
    tc2 = wave_reduce(tc2); tc3 = wave_reduce(tc3);
    if (lane == 0) {
        red[wave][0] = tc0; red[wave][1] = tc1;
        red[wave][2] = tc2; red[wave][3] = tc3;
    }
    __syncthreads();
    if (tid < 4)
        atomicAdd(&scal[tid], red[0][tid] + red[1][tid] + red[2][tid] + red[3][tid]);
}

// ---------------- kernel 3: final reduction + scalar math ----------------
__global__ __launch_bounds__(1024) void k3_final(
        const float* __restrict__ rows, const float* __restrict__ scal,
        const float* __restrict__ wts, const float* __restrict__ kpart,
        float* __restrict__ out, int N) {
    __shared__ float red[16][14];
    __shared__ float fin[12];
    int tid = threadIdx.x, lane = tid & 63, wave = tid >> 6;

    if (wave == 0) {
#pragma unroll
        for (int k = 0; k < 12; ++k) {
            float v = (lane < 32) ? kpart[lane * 12 + k] : 0.f;
            v = wave_reduce(v);
            if (lane == 0) fin[k] = v;
        }
    }

    float acc[14];
#pragma unroll
    for (int k = 0; k < 14; ++k) acc[k] = 0.f;

    for (int i = tid; i < N; i += 1024) {
        float w = wts[i];
        float s0 = rows[0 * N + i], s1 = rows[1 * N + i], s2 = rows[2 * N + i],
              s3 = rows[3 * N + i], sE = rows[4 * N + i];
        acc[0] += w * s0; acc[1] += w * s1; acc[2] += w * s2;
        acc[3] += w * s3; acc[4] += w * sE;
        float wE = w * sE;
        acc[5] += wE * s0; acc[6] += wE * s1; acc[7] += wE * s2; acc[8] += wE * s3;
        acc[9] += wE * sE;
        acc[10] += w * s0 * s0; acc[11] += w * s1 * s1;
        acc[12] += w * s2 * s2; acc[13] += w * s3 * s3;
    }

#pragma unroll
    for (int k = 0; k < 14; ++k) acc[k] = wave_reduce(acc[k]);
    if (lane == 0) {
#pragma unroll
        for (int k = 0; k < 14; ++k) red[wave][k] = acc[k];
    }
    __syncthreads();

    if (tid == 0) {
        float SW[5], SWW_ce[4], SWW_ee, SWW_cc[4];
#pragma unroll
        for (int k = 0; k < 5; ++k) {
            float a = 0.f;
            for (int wv = 0; wv < 16; ++wv) a += red[wv][k];
            SW[k] = a;
        }
#pragma unroll
        for (int k = 0; k < 4; ++k) {
            float a = 0.f;
            for (int wv = 0; wv < 16; ++wv) a += red[wv][5 + k];
            SWW_ce[k] = a;
        }
        {
            float a = 0.f;
            for (int wv = 0; wv < 16; ++wv) a += red[wv][9];
            SWW_ee = a;
        }
#pragma unroll
        for (int k = 0; k < 4; ++k) {
            float a = 0.f;
            for (int wv = 0; wv < 16; ++wv) a += red[wv][10 + k];
            SWW_cc[k] = a;
        }

        float focal_sum = fin[0];
        float W = fin[1];
        float M1[5] = {fin[2], fin[3], fin[4], fin[5], fin[6]};
        float M2[5] = {fin[7], fin[8], fin[9], fin[10], fin[11]};

        float invW2 = 1.0f / (W * W);
        float invW3 = invW2 / W;

        float g[5];
#pragma unroll
        for (int v = 0; v < 5; ++v) g[v] = SW[v] * invW2;
        float gE = g[4];

        // closed-form same-channel raw T: 2*(W*M2 - M1^2)
        float Tee = 2.0f * (W * M2[4] - M1[4] * M1[4]);
        float num_ee = Tee * invW2 - 2.0f * SWW_ee * invW3 + gE * gE;

        float disco = 0.f;
#pragma unroll
        for (int c = 0; c < 4; ++c) {
            float Tcc = 2.0f * (W * M2[c] - M1[c] * M1[c]);
            float num_cc = Tcc * invW2 - 2.0f * SWW_cc[c] * invW3 + g[c] * g[c];
            float num_ce = scal[c] * invW2 - 2.0f * SWW_ce[c] * invW3 + g[c] * gE;
            disco += num_ce * rsqrtf(num_cc * num_ee);
        }
        disco *= 0.25f;

        float f = focal_sum / (float)N;
        out[0] = f;
        out[1] = disco;
        out[2] = f + LAM * disco;
    }
}

extern "C" void kernel_launch(void* const* d_in, const int* in_sizes, int n_in,
                              void* d_out, int out_size, void* d_ws, size_t ws_size,
                              hipStream_t stream) {
    const float* outs = (const float*)d_in[0];
    const int* labels = (const int*)d_in[1];
    const float* event = (const float*)d_in[2];
    const float* wts = (const float*)d_in[3];
    float* out = (float*)d_out;
    int N = in_sizes[1];  // 8192

    float* ws = (float*)d_ws;
    float* probs = ws;                    // 4N
    float* rows = probs + (size_t)N * 4;  // 5N
    float* scal = rows + (size_t)N * 5;   // 16
    float* kpart = scal + 16;             // 32*12

    k1_rowprep<<<N / BLK, BLK, 0, stream>>>(outs, labels, event, wts, probs,
                                            rows, scal, kpart, N);

    dim3 g2(N / (BLK * IT), JSPLIT);   // (8, 128) = 1024 blocks
    k2_pairs<<<g2, BLK, 0, stream>>>((const float4*)probs, event, wts, rows, scal, N);

    k3_final<<<1, 1024, 0, stream>>>(rows, scal, wts, kpart, out, N);
}